// Round 16
// baseline (175.312 us; speedup 1.0000x reference)
//
#include <hip/hip_runtime.h>
#include <cstdint>
#include <cstddef>
#include <utility>

#define SS 512
#define TT 32
#define NB 256
#define KSTEPS 510   // SS-2
#define PQUADS 128   // pstore quads per batch (4 rows each)

// ---------- unroll helper (compile-time indices -> registers) ----------
template <typename F, size_t... Is>
__device__ __forceinline__ void unroll_impl(F&& f, std::index_sequence<Is...>) {
  (f(std::integral_constant<int, (int)Is>{}), ...);
}
template <int N, typename F>
__device__ __forceinline__ void unrollN(F&& f) {
  unroll_impl(f, std::make_index_sequence<N>{});
}

// butterfly xor D within each 32-lane group (one-time reductions only)
template <int D>
__device__ __forceinline__ float bfly32(float v) {
  return __int_as_float(__builtin_amdgcn_ds_swizzle(__float_as_int(v), (D << 10) | 0x1f));
}
template <int D>
__device__ __forceinline__ int bfly32i(int v) {
  return __builtin_amdgcn_ds_swizzle(v, (D << 10) | 0x1f);
}

__device__ __forceinline__ float max3f(float a, float b, float c) {
  return fmaxf(fmaxf(a, b), c);  // fuses to v_max3_f32; fmax exact in any grouping
}

// ---- cross-half combine, orientation-proof (r14-verified) ----
__device__ __forceinline__ float combine_max32(float m) {
#if __has_builtin(__builtin_amdgcn_permlane32_swap)
  auto r = __builtin_amdgcn_permlane32_swap(__float_as_uint(m), __float_as_uint(m), false, false);
  return fmaxf(__uint_as_float(r[0]), __uint_as_float(r[1]));
#else
  return fmaxf(m, __shfl_xor(m, 32, 64));
#endif
}
__device__ __forceinline__ float combine_sum32(float m) {
#if __has_builtin(__builtin_amdgcn_permlane32_swap)
  auto r = __builtin_amdgcn_permlane32_swap(__float_as_uint(m), __float_as_uint(m), false, false);
  return __uint_as_float(r[0]) + __uint_as_float(r[1]);
#else
  return m + __shfl_xor(m, 32, 64);
#endif
}

// ---------- mask dtype autodetect (bool may arrive as i32 / u8 / f32) ----------
__device__ __forceinline__ int mask_mode(const void* m) {
  int w0 = ((const int*)m)[0];
  if (w0 == 1) return 0;                // int32 0/1
  if (w0 == 0x3f800000) return 2;       // float32 1.0
  return 1;                             // uint8
}
__device__ __forceinline__ bool mask_at(const void* m, int idx, int mode) {
  if (mode == 0) return ((const int*)m)[idx] != 0;
  if (mode == 2) return ((const float*)m)[idx] != 0.0f;
  return ((const unsigned char*)m)[idx] != 0;
}

// per-wave sequence length (lane in [0,64)); result uniform (SGPR)
__device__ __forceinline__ int seq_length_lane(const void* mask, int b, int lane, int mode) {
  int cnt = 0;
  for (int s = lane; s < SS; s += 64) cnt += mask_at(mask, b * SS + s, mode) ? 1 : 0;
  for (int d = 1; d < 64; d <<= 1) cnt += __shfl_xor(cnt, d, 64);
  return __builtin_amdgcn_readfirstlane(cnt);
}

// ---------- K1: paired chains (2 batches per wave) ----------
// Blocks 0..127: forward pairs; 128..255: viterbi pairs; 256..511: gold.
// Per iteration: BOTH chains' 4 uniform ds_read_b128 issue first, then
// chain A computes/writes, then chain B (register-only VALU overlaps A's
// write + B's reads landed during A's compute). Separate 128B qlds each.
__global__ __launch_bounds__(64, 1) void crf_main_kernel(
    const float* __restrict__ feats, const float* __restrict__ trans,
    const void* __restrict__ mask, const int* __restrict__ tags,
    float* __restrict__ pstore, float* __restrict__ ws_fwd,
    float* __restrict__ ws_gold, int* __restrict__ ws_ptr) {
  const int blk = blockIdx.x;
  const int tid = threadIdx.x;
  const int mode = mask_mode(mask);
  const int j = tid & 31;   // owned tag
  const int h = tid >> 5;   // source half

  __shared__ __align__(16) float qlds[2][TT];

  if (blk < 128) {
    // ========== FORWARD pair, exp-space: q' = exp(f) * (E^T q) ==========
    const int bA = blk * 2, bB = bA + 1;
    const int stepsA = seq_length_lane(mask, bA, tid, mode) - 2;
    const int stepsB = seq_length_lane(mask, bB, tid, mode) - 2;
    const int smax = (stepsA > stepsB) ? stepsA : stepsB;
    const float* fbA = feats + (size_t)bA * (SS * TT) + j;
    const float* fbB = feats + (size_t)bB * (SS * TT) + j;

    float E[16];  // rows 16h..16h+15 of exp(trans), column j
    unrollN<16>([&](auto I) {
      constexpr int ii = I;
      E[ii] = __expf(trans[(h * 16 + ii) * TT + j]);
    });

    float qA = __expf(fbA[TT]), qB = __expf(fbB[TT]);
    int EaA = 0, EaB = 0;
    qlds[0][j] = qA; qlds[1][j] = qB;
    asm volatile("" ::: "memory");
    const float4* qvA = (const float4*)qlds[0] + h * 4;
    const float4* qvB = (const float4*)qlds[1] + h * 4;

    float fA0 = fbA[2 * TT], fB0 = fbA[3 * TT], fC0 = fbA[4 * TT];
    float fA1 = fbB[2 * TT], fB1 = fbB[3 * TT], fC1 = fbB[4 * TT];
    float efA = __expf(fA0), efB = __expf(fA1);

    auto fstep2 = [&](int k, bool resc) {
      // both chains' reads issue first
      float4 QA0 = qvA[0], QA1 = qvA[1], QA2 = qvA[2], QA3 = qvA[3];
      float4 QB0 = qvB[0], QB1 = qvB[1], QB2 = qvB[2], QB3 = qvB[3];
      int r5 = k + 5; r5 = (r5 < SS) ? r5 : (SS - 1);
      float fDA = fbA[r5 * TT], fDB = fbB[r5 * TT];   // prefetch (off-chain)
      float efNA = __expf(fB0), efNB = __expf(fB1);   // next exps (off-chain)
      // ---- chain A ----
      {
        float a0, a1, a2, a3;
        a0 = QA0.x * E[0];  a1 = QA0.y * E[1];  a2 = QA0.z * E[2];  a3 = QA0.w * E[3];
        a0 = fmaf(QA1.x, E[4], a0);  a1 = fmaf(QA1.y, E[5], a1);  a2 = fmaf(QA1.z, E[6], a2);  a3 = fmaf(QA1.w, E[7], a3);
        a0 = fmaf(QA2.x, E[8], a0);  a1 = fmaf(QA2.y, E[9], a1);  a2 = fmaf(QA2.z, E[10], a2); a3 = fmaf(QA2.w, E[11], a3);
        a0 = fmaf(QA3.x, E[12], a0); a1 = fmaf(QA3.y, E[13], a1); a2 = fmaf(QA3.z, E[14], a2); a3 = fmaf(QA3.w, E[15], a3);
        float P = (a0 + a1) + (a2 + a3);
        float qn = efA * combine_sum32(P);
        if (resc) {
          int e = (__float_as_int(QA0.x) >> 23) & 0xff;  // uniform
          e = (k < stepsA) ? e : 127;
          EaA += e - 127;
          qn *= __int_as_float((254 - e) << 23);
        }
        qn = (k < stepsA) ? qn : qA;
        qA = qn;
        qlds[0][j] = qn;
        asm volatile("" ::: "memory");
      }
      // ---- chain B (register-only until its write) ----
      {
        float a0, a1, a2, a3;
        a0 = QB0.x * E[0];  a1 = QB0.y * E[1];  a2 = QB0.z * E[2];  a3 = QB0.w * E[3];
        a0 = fmaf(QB1.x, E[4], a0);  a1 = fmaf(QB1.y, E[5], a1);  a2 = fmaf(QB1.z, E[6], a2);  a3 = fmaf(QB1.w, E[7], a3);
        a0 = fmaf(QB2.x, E[8], a0);  a1 = fmaf(QB2.y, E[9], a1);  a2 = fmaf(QB2.z, E[10], a2); a3 = fmaf(QB2.w, E[11], a3);
        a0 = fmaf(QB3.x, E[12], a0); a1 = fmaf(QB3.y, E[13], a1); a2 = fmaf(QB3.z, E[14], a2); a3 = fmaf(QB3.w, E[15], a3);
        float P = (a0 + a1) + (a2 + a3);
        float qn = efB * combine_sum32(P);
        if (resc) {
          int e = (__float_as_int(QB0.x) >> 23) & 0xff;
          e = (k < stepsB) ? e : 127;
          EaB += e - 127;
          qn *= __int_as_float((254 - e) << 23);
        }
        qn = (k < stepsB) ? qn : qB;
        qB = qn;
        qlds[1][j] = qn;
        asm volatile("" ::: "memory");
      }
      fA0 = fB0; fB0 = fC0; fC0 = fDA; efA = efNA;
      fA1 = fB1; fB1 = fC1; fC1 = fDB; efB = efNB;
    };

    int k = 0;
    for (; k + 4 <= smax; k += 4) {
      fstep2(k, false); fstep2(k + 1, false); fstep2(k + 2, false); fstep2(k + 3, true);
    }
    for (; k < smax; ++k) fstep2(k, false);

    float sA = qA, sB = qB;
    unrollN<5>([&](auto D) { constexpr int d = 1 << D; sA += bfly32<d>(sA); });
    unrollN<5>([&](auto D) { constexpr int d = 1 << D; sB += bfly32<d>(sB); });
    if (tid == 0) {
      ws_fwd[bA] = __logf(sA) + (float)EaA * 0.69314718056f;
      ws_fwd[bB] = __logf(sB) + (float)EaB * 0.69314718056f;
    }

  } else if (blk < 256) {
    // ================= VITERBI pair (max only; bp deferred to K2) =================
    const int bA = (blk - 128) * 2, bB = bA + 1;
    const int stepsA = seq_length_lane(mask, bA, tid, mode) - 2;
    const int stepsB = seq_length_lane(mask, bB, tid, mode) - 2;
    const int smax = (stepsA > stepsB) ? stepsA : stepsB;
    const float* fbA = feats + (size_t)bA * (SS * TT) + j;
    const float* fbB = feats + (size_t)bB * (SS * TT) + j;
    float* pqA = pstore + (size_t)bA * (PQUADS * 128) + j * 4;
    float* pqB = pstore + (size_t)bB * (PQUADS * 128) + j * 4;

    float C[16];  // rows 16h..16h+15 of trans, column j
    unrollN<16>([&](auto I) {
      constexpr int ii = I;
      C[ii] = trans[(h * 16 + ii) * TT + j];
    });

    float pA = fbA[TT], pB = fbB[TT];
    qlds[0][j] = pA; qlds[1][j] = pB;
    asm volatile("" ::: "memory");
    const float4* qvA = (const float4*)qlds[0] + h * 4;
    const float4* qvB = (const float4*)qlds[1] + h * 4;

    float fA0 = fbA[2 * TT], fB0 = fbA[3 * TT], fC0 = fbA[4 * TT];
    float fA1 = fbB[2 * TT], fB1 = fbB[3 * TT], fC1 = fbB[4 * TT];
    float h0A = pA, h1A = 0.f, h2A = 0.f, h3A = 0.f;
    float h0B = pB, h1B = 0.f, h2B = 0.f, h3B = 0.f;

    auto vstep2 = [&](int k, float& hA, float& hB) {
      // both chains' reads issue first
      float4 QA0 = qvA[0], QA1 = qvA[1], QA2 = qvA[2], QA3 = qvA[3];
      float4 QB0 = qvB[0], QB1 = qvB[1], QB2 = qvB[2], QB3 = qvB[3];
      int r5 = k + 5; r5 = (r5 < SS) ? r5 : (SS - 1);
      float fDA = fbA[r5 * TT], fDB = fbB[r5 * TT];
      // ---- chain A ----
      {
        float dd[16];
        unrollN<16>([&](auto I) { constexpr int ii = I; dd[ii] = fA0 + C[ii]; });
        float cur[16];
        cur[0] = QA0.x + dd[0];   cur[1] = QA0.y + dd[1];   cur[2] = QA0.z + dd[2];   cur[3] = QA0.w + dd[3];
        cur[4] = QA1.x + dd[4];   cur[5] = QA1.y + dd[5];   cur[6] = QA1.z + dd[6];   cur[7] = QA1.w + dd[7];
        cur[8] = QA2.x + dd[8];   cur[9] = QA2.y + dd[9];   cur[10] = QA2.z + dd[10]; cur[11] = QA2.w + dd[11];
        cur[12] = QA3.x + dd[12]; cur[13] = QA3.y + dd[13]; cur[14] = QA3.z + dd[14]; cur[15] = QA3.w + dd[15];
        float t0 = max3f(cur[0], cur[1], cur[2]);
        float t1 = max3f(cur[3], cur[4], cur[5]);
        float t2 = max3f(cur[6], cur[7], cur[8]);
        float t3 = max3f(cur[9], cur[10], cur[11]);
        float t4 = max3f(cur[12], cur[13], cur[14]);
        float m = fmaxf(max3f(t0, t1, t2), max3f(t3, t4, cur[15]));
        float pw = combine_max32(m);
        pw = (k < stepsA) ? pw : pA;
        pA = pw;
        qlds[0][j] = pw;
        asm volatile("" ::: "memory");
        hA = pw;
      }
      // ---- chain B ----
      {
        float dd[16];
        unrollN<16>([&](auto I) { constexpr int ii = I; dd[ii] = fA1 + C[ii]; });
        float cur[16];
        cur[0] = QB0.x + dd[0];   cur[1] = QB0.y + dd[1];   cur[2] = QB0.z + dd[2];   cur[3] = QB0.w + dd[3];
        cur[4] = QB1.x + dd[4];   cur[5] = QB1.y + dd[5];   cur[6] = QB1.z + dd[6];   cur[7] = QB1.w + dd[7];
        cur[8] = QB2.x + dd[8];   cur[9] = QB2.y + dd[9];   cur[10] = QB2.z + dd[10]; cur[11] = QB2.w + dd[11];
        cur[12] = QB3.x + dd[12]; cur[13] = QB3.y + dd[13]; cur[14] = QB3.z + dd[14]; cur[15] = QB3.w + dd[15];
        float t0 = max3f(cur[0], cur[1], cur[2]);
        float t1 = max3f(cur[3], cur[4], cur[5]);
        float t2 = max3f(cur[6], cur[7], cur[8]);
        float t3 = max3f(cur[9], cur[10], cur[11]);
        float t4 = max3f(cur[12], cur[13], cur[14]);
        float m = fmaxf(max3f(t0, t1, t2), max3f(t3, t4, cur[15]));
        float pw = combine_max32(m);
        pw = (k < stepsB) ? pw : pB;
        pB = pw;
        qlds[1][j] = pw;
        asm volatile("" ::: "memory");
        hB = pw;
      }
      fA0 = fB0; fB0 = fC0; fC0 = fDA;
      fA1 = fB1; fB1 = fC1; fC1 = fDB;
    };

    auto flushA = [&](int quad) {
      if (tid < 32) { float4 v; v.x = h0A; v.y = h1A; v.z = h2A; v.w = h3A; *(float4*)(pqA + quad * 128) = v; }
    };
    auto flushB = [&](int quad) {
      if (tid < 32) { float4 v; v.x = h0B; v.y = h1B; v.z = h2B; v.w = h3B; *(float4*)(pqB + quad * 128) = v; }
    };

    int k = 0;
    for (; k + 4 <= smax; k += 4) {
      vstep2(k, h1A, h1B);
      vstep2(k + 1, h2A, h2B);
      vstep2(k + 2, h3A, h3B);
      flushA(k >> 2); flushB(k >> 2);
      vstep2(k + 3, h0A, h0B);
    }
    if (k < smax) vstep2(k, h1A, h1B);
    if (k + 1 < smax) vstep2(k + 1, h2A, h2B);
    if (k + 2 < smax) vstep2(k + 2, h3A, h3B);
    flushA(k >> 2); flushB(k >> 2);

    // pointers = first-max argmax over tags of final partitions
    auto finArg = [&](float p, int bb) {
      float v = p;
      int idx = j;
      unrollN<5>([&](auto D) {
        constexpr int d = 1 << D;
        float vo = bfly32<d>(v);
        int io = bfly32i<d>(idx);
        bool take = (vo > v) || ((vo == v) && (io < idx));
        v = take ? vo : v;
        idx = take ? io : idx;
      });
      if (tid == 0) ws_ptr[bb] = idx;
    };
    finArg(pA, bA);
    finArg(pB, bB);

  } else {
    // ================= GOLD SCORE =================
    const int b = blk - 256;
    float acc = 0.0f;
    for (int s = tid; s < SS; s += 64) {
      if (s == 0) continue;
      if (!mask_at(mask, b * SS + s, mode)) continue;
      int tg = tags[b * SS + s];
      if (tg == -100) tg = 0;
      float e = feats[((size_t)b * SS + s) * TT + tg];
      if (s >= 2) {
        int tp = tags[b * SS + s - 1];
        if (tp == -100) tp = 0;
        e += trans[tp * TT + tg];
      }
      acc += e;
    }
    for (int d = 1; d < 64; d <<= 1) acc += __shfl_xor(acc, d, 64);
    if (tid == 0) ws_gold[b] = acc;
  }
}

// ---------- K2: parallel bp recompute + chunked backtrace + finish ----------
__global__ __launch_bounds__(512) void crf_backtrace_kernel(
    const float* __restrict__ pstore, const float* __restrict__ feats,
    const float* __restrict__ trans, const void* __restrict__ mask,
    const int* __restrict__ ws_ptr, const float* __restrict__ ws_fwd,
    const float* __restrict__ ws_gold, float* __restrict__ out) {
  __shared__ unsigned char bp[KSTEPS * TT];         // 16320 B
  __shared__ unsigned char path[KSTEPS * TT];       // 16320 B
  __shared__ __align__(16) float pT[16][4][TT];     // 8 KB transpose staging
  __shared__ int entries[8];

  const int b = blockIdx.x;
  const int tid = threadIdx.x;
  const int mode = mask_mode(mask);
  const int lane = tid & 63;
  float* out_decode = out + 1 + NB;

  const int steps = seq_length_lane(mask, b, lane, mode) - 2;

  if (tid == 0) out[1 + b] = 0.0f;  // path_score = zeros(B)
  if (b == 0 && tid >= 64 && tid < 128) {
    int t = tid - 64;
    float sf = 0.0f, sg = 0.0f;
    for (int r = 0; r < 4; ++r) { sf += ws_fwd[t + 64 * r]; sg += ws_gold[t + 64 * r]; }
    for (int d = 1; d < 64; d <<= 1) { sf += __shfl_xor(sf, d, 64); sg += __shfl_xor(sg, d, 64); }
    if (t == 0) out[0] = (sf - sg) / 256.0f;
  }

  // ---- parallel bp recompute, quad-based (r15-verified)
  {
    const int jj = tid & 31;
    const int g = tid >> 5;
    float Cc[TT];
    unrollN<TT>([&](auto I) { constexpr int ii = I; Cc[ii] = trans[ii * TT + jj]; });
    const float* pb = pstore + (size_t)b * (PQUADS * 128);
    const float* fbb = feats + (size_t)b * (SS * TT);
    for (int q = g; q < PQUADS; q += 16) {
      float4 V = *(const float4*)(pb + q * 128 + jj * 4);  // coalesced 512B/group
      pT[g][0][jj] = V.x; pT[g][1][jj] = V.y; pT[g][2][jj] = V.z; pT[g][3][jj] = V.w;
      asm volatile("" ::: "memory");
      unrollN<4>([&](auto R) {
        constexpr int r = R;
        const int k = 4 * q + r;
        if (k < KSTEPS) {
          unsigned char bv = 0;
          if (k < steps) {
            const float4* pr = (const float4*)pT[g][r];   // uniform per group
            float4 P0 = pr[0], P1 = pr[1], P2 = pr[2], P3 = pr[3];
            float4 P4 = pr[4], P5 = pr[5], P6 = pr[6], P7 = pr[7];
            float fj = fbb[(k + 2) * TT + jj];
            float cur[TT];  // fl(fl(f+tr) + p): identical floats to K1's chain
            cur[0]  = (fj + Cc[0])  + P0.x; cur[1]  = (fj + Cc[1])  + P0.y;
            cur[2]  = (fj + Cc[2])  + P0.z; cur[3]  = (fj + Cc[3])  + P0.w;
            cur[4]  = (fj + Cc[4])  + P1.x; cur[5]  = (fj + Cc[5])  + P1.y;
            cur[6]  = (fj + Cc[6])  + P1.z; cur[7]  = (fj + Cc[7])  + P1.w;
            cur[8]  = (fj + Cc[8])  + P2.x; cur[9]  = (fj + Cc[9])  + P2.y;
            cur[10] = (fj + Cc[10]) + P2.z; cur[11] = (fj + Cc[11]) + P2.w;
            cur[12] = (fj + Cc[12]) + P3.x; cur[13] = (fj + Cc[13]) + P3.y;
            cur[14] = (fj + Cc[14]) + P3.z; cur[15] = (fj + Cc[15]) + P3.w;
            cur[16] = (fj + Cc[16]) + P4.x; cur[17] = (fj + Cc[17]) + P4.y;
            cur[18] = (fj + Cc[18]) + P4.z; cur[19] = (fj + Cc[19]) + P4.w;
            cur[20] = (fj + Cc[20]) + P5.x; cur[21] = (fj + Cc[21]) + P5.y;
            cur[22] = (fj + Cc[22]) + P5.z; cur[23] = (fj + Cc[23]) + P5.w;
            cur[24] = (fj + Cc[24]) + P6.x; cur[25] = (fj + Cc[25]) + P6.y;
            cur[26] = (fj + Cc[26]) + P6.z; cur[27] = (fj + Cc[27]) + P6.w;
            cur[28] = (fj + Cc[28]) + P7.x; cur[29] = (fj + Cc[29]) + P7.y;
            cur[30] = (fj + Cc[30]) + P7.z; cur[31] = (fj + Cc[31]) + P7.w;
            float t0 = max3f(cur[0], cur[1], cur[2]);
            float t1 = max3f(cur[3], cur[4], cur[5]);
            float t2 = max3f(cur[6], cur[7], cur[8]);
            float t3 = max3f(cur[9], cur[10], cur[11]);
            float t4 = max3f(cur[12], cur[13], cur[14]);
            float t5 = max3f(cur[15], cur[16], cur[17]);
            float t6 = max3f(cur[18], cur[19], cur[20]);
            float t7 = max3f(cur[21], cur[22], cur[23]);
            float t8 = max3f(cur[24], cur[25], cur[26]);
            float t9 = max3f(cur[27], cur[28], cur[29]);
            float ta = fmaxf(cur[30], cur[31]);
            float vmax = fmaxf(fmaxf(max3f(t0, t1, t2), max3f(t3, t4, t5)),
                               fmaxf(max3f(t6, t7, t8), fmaxf(t9, ta)));
            int bi = 31;  // first-max (descending overwrite-on-equal = jnp.argmax)
            unrollN<TT>([&](auto I) { constexpr int ii = 31 - I; bi = (cur[ii] == vmax) ? ii : bi; });
            bv = (unsigned char)bi;
          }
          bp[k * TT + jj] = bv;
        }
      });
    }
  }
  __syncthreads();

  // ---- chunked-hypothesis backtrace (each wave = one 64-step chunk)
  const int wave = tid >> 6;
  if (lane < 32) {
    const int lo = wave * 64;
    const int hi = (lo + 64 < KSTEPS) ? (lo + 64) : KSTEPS;
    int ptr = lane;
    for (int k = hi - 1; k >= lo; --k) {
      ptr = bp[k * TT + ptr];
      path[k * TT + lane] = (unsigned char)ptr;
    }
  }
  __syncthreads();

  // compose chunk entries from the top (chunk 7 enters with pointer)
  if (tid == 0) {
    int e = ws_ptr[b];
    for (int c = 7; c >= 0; --c) {
      entries[c] = e;
      e = path[(c * 64) * TT + e];
    }
  }
  __syncthreads();

  // decode row: [0, ptrs[0..509], pointer]
  const int s = tid;
  int val;
  if (s == 0) val = 0;
  else if (s <= KSTEPS) { int k = s - 1; val = path[k * TT + entries[k >> 6]]; }
  else val = ws_ptr[b];
  out_decode[(size_t)b * SS + s] = (float)val;
}

extern "C" void kernel_launch(void* const* d_in, const int* in_sizes, int n_in,
                              void* d_out, int out_size, void* d_ws, size_t ws_size,
                              hipStream_t stream) {
  const float* feats = (const float*)d_in[0];
  const float* trans = (const float*)d_in[1];
  const void* mask = d_in[2];
  const int* tags = (const int*)d_in[3];
  float* out = (float*)d_out;

  unsigned char* ws = (unsigned char*)d_ws;
  const size_t PST_BYTES = (size_t)NB * PQUADS * 128 * 4;  // 16,777,216
  float* pstore = (float*)ws;
  float* ws_fwd = (float*)(ws + PST_BYTES);
  float* ws_gold = (float*)(ws + PST_BYTES + 2048);
  int* ws_ptr = (int*)(ws + PST_BYTES + 4096);

  hipLaunchKernelGGL(crf_main_kernel, dim3(512), dim3(64), 0, stream,
                     feats, trans, mask, tags, pstore, ws_fwd, ws_gold, ws_ptr);
  hipLaunchKernelGGL(crf_backtrace_kernel, dim3(NB), dim3(512), 0, stream,
                     pstore, feats, trans, mask, ws_ptr, ws_fwd, ws_gold, out);
}